// Round 7
// baseline (227.575 us; speedup 1.0000x reference)
//
#include <hip/hip_runtime.h>

// Radon transform, MI355X. B=4, IMG=256, NA=512.
// R7: VALU-bound fix. 16-row slabs -> quad LDS 39 KB -> 4 blocks/CU (32
// waves); each block does 2 consecutive slabs sequentially (restage) so ws
// partials stay at 8 groups. Lean 16-VALU sample: pk_add_f32 coord advance,
// med3 clamps both axes (also fixes trunc/fract at slab row-0), one-instr
// pkrtz(wr,wr) broadcast, no swizzle, no e-clamp. Col-mode stages directly
// from img (stride-256, L2-resident) -> transpose kernel deleted.

typedef _Float16 f16;
typedef _Float16 f16x2 __attribute__((ext_vector_type(2)));
typedef _Float16 f16x4 __attribute__((ext_vector_type(4)));
typedef __fp16   h16x2 __attribute__((ext_vector_type(2)));
typedef float    f32x2 __attribute__((ext_vector_type(2)));

#define CST   19                 // quad col stride in 8B words (odd)
#define NQR   18                 // quad rows per slab (Ri in [0,17])
#define NC    257                // pair-columns X = 0..256
#define LDSQ  (NC * CST)         // 4883 8B words = 39,064 B

// one bilinear sample: quad (X,Ri) = {P[r][X-1],P[r][X],P[r+1][X-1],P[r+1][X]},
// r = rbase+Ri. ONE ds_read_b64; packed f16 vertical lerp; fdot2 epilogue.
#define SAMP(POS, ACC) do {                                       \
    float pc_ = __builtin_amdgcn_fmed3f((POS).x, 0.0f, 256.999f); \
    float pr_ = __builtin_amdgcn_fmed3f((POS).y, 0.0f, 17.999f);  \
    int   Xi_ = (int)pc_;                                         \
    int   Ri_ = (int)pr_;                                         \
    float wc_ = __builtin_amdgcn_fractf(pc_);                     \
    float wr_ = __builtin_amdgcn_fractf(pr_);                     \
    f16x4 qd_ = lds4[Xi_ * CST + Ri_];                            \
    f16x2 lo_ = __builtin_shufflevector(qd_, qd_, 0, 1);          \
    f16x2 hi_ = __builtin_shufflevector(qd_, qd_, 2, 3);          \
    f16x2 wv_ = __builtin_bit_cast(f16x2, __builtin_amdgcn_cvt_pkrtz(wr_, wr_)); \
    f16x2 t_  = lo_ + wv_ * (hi_ - lo_);                          \
    h16x2 wp_ = __builtin_amdgcn_cvt_pkrtz(1.0f - wc_, wc_);      \
    (ACC) = __builtin_amdgcn_fdot2(__builtin_bit_cast(h16x2, t_), wp_, (ACC), false); \
} while (0)

__global__ __launch_bounds__(512, 8) void radon_k(const float* __restrict__ img,
                                                  float* __restrict__ ws2) {
    __shared__ f16x4 lds4[LDSQ];
    const int tid = threadIdx.x;
    const int bx  = blockIdx.x;                 // 2048 = b(4) x g(64) x q2(8)
    const int q2 = bx & 7, g = (bx >> 3) & 63, b = bx >> 9;
    const bool colC = (g >= 16) && (g < 48);    // a in [128,384): column slabs
    const float* src = img + (b << 16);

    const int   w   = tid & 255, sub = tid >> 8;  // angle uniform per wave
    const float xw  = (float)w - 127.5f;

    float acc[4] = {0.f, 0.f, 0.f, 0.f};

    for (int s = 0; s < 2; ++s) {
        const int q = (q2 << 1) | s;            // slab 0..15
        const int rbase = (q << 4) - 1;         // 19 staged rows: rbase..rbase+18
        if (s) __syncthreads();                 // drain slab-0 compute

        // ---- stage: u -> (rr, X), X fastest for row-mode coalescing.
        // Col-mode view P[r][c] = img[c*256 + r] (strided reads, L2-resident).
        for (int u = tid; u < NC * NQR; u += 512) {
            int rr = u / NC;                    // 0..17
            int X  = u - rr * NC;               // 0..256
            int r0 = rbase + rr;                // quad rows r0, r0+1
            float a0 = 0.f, b0 = 0.f, a1 = 0.f, b1 = 0.f;
            const bool r0v = (unsigned)r0 < 256u, r1v = (unsigned)(r0 + 1) < 256u;
            if (!colC) {
                const float* rp = src + (r0 << 8);
                const bool c0 = X > 0, c1 = X < 256;
                if (r0v) { if (c0) a0 = rp[X - 1];       if (c1) b0 = rp[X]; }
                if (r1v) { if (c0) a1 = rp[256 + X - 1]; if (c1) b1 = rp[256 + X]; }
            } else {
                if (X > 0)   { const float* cp = src + ((X - 1) << 8);
                               if (r0v) a0 = cp[r0]; if (r1v) a1 = cp[r0 + 1]; }
                if (X < 256) { const float* cp = src + (X << 8);
                               if (r0v) b0 = cp[r0]; if (r1v) b1 = cp[r0 + 1]; }
            }
            f16x4 w4; w4.x = (f16)a0; w4.y = (f16)b0; w4.z = (f16)a1; w4.w = (f16)b1;
            lds4[X * CST + rr] = w4;
        }
        __syncthreads();

        // band [B0,B1) on the slab axis; nonzero samples have coord in (-1,256)
        const float B0 = (q == 0)  ? -1.0f  : (float)(q << 4);
        const float B1 = (q == 15) ? 256.0f : (float)((q << 4) + 16);

#pragma unroll
        for (int k = 0; k < 4; ++k) {
            const int a = (g << 3) | (k << 1) | sub;
            const float th  = (float)a * 6.1359231515425649e-3f;   // a*pi/512
            const float sth = __sinf(th), cth = __cosf(th);        // block-consistent
            const float Ax = fmaf(cth, xw, fmaf(sth, -127.5f, 127.5f));
            const float Ay = fmaf(-sth, xw, fmaf(cth, -127.5f, 127.5f));
            float cs, As, rs, Ar;                // col coord / row(slab) coord roles
            if (colC) { cs = cth; As = Ay; rs = sth; Ar = Ax; }
            else      { cs = sth; As = Ax; rs = cth; Ar = Ay; }

            // slab ownership: r(h)=Ar+h*rs in [B0,B1); |rs|>=0.707; exact
            // ceil/floor partition (adjacent q share identical boundary floats)
            const float invr = 1.0f / rs;
            const float tA = (B0 - Ar) * invr, tB = (B1 - Ar) * invr;
            int h0, h1;
            if (rs > 0.f) { h0 = (int)ceilf(tA);      h1 = (int)ceilf(tB) - 1; }
            else          { h0 = (int)floorf(tB) + 1; h1 = (int)floorf(tA);   }

            // col validity v(h)=As+h*cs in (-1,256); cs signed, may be ~0
            if (cs != 0.f) {
                const float invc = 1.0f / cs;
                float ta = (-1.0f - As) * invc, tb = (256.0f - As) * invc;
                ta = fmaxf(fminf(ta, 400.f), -400.f);
                tb = fmaxf(fminf(tb, 400.f), -400.f);
                if (cs > 0.f) { h0 = max(h0, (int)ceilf(ta));      h1 = min(h1, (int)ceilf(tb) - 1); }
                else          { h0 = max(h0, (int)floorf(tb) + 1); h1 = min(h1, (int)floorf(ta));   }
            } else if (As <= -1.f || As >= 256.f) {
                h1 = h0 - 1;
            }
            h0 = max(h0, 0); h1 = min(h1, 255);

            if (h0 <= h1) {
                const float h0f = (float)h0;
                f32x2 pos0, st;
                pos0.x = fmaf(h0f, cs, As + 1.0f);           // col coord + 1
                pos0.y = fmaf(h0f, rs, Ar - (float)rbase);   // slab-local row
                st.x = cs; st.y = rs;
                f32x2 posA = pos0, posB = pos0 + st;
                const f32x2 st2 = st + st;
                float a0 = 0.f, a1 = 0.f;
                const int n = h1 - h0 + 1;                   // <= 24
                for (int i = 0; i + 2 <= n; i += 2) {        // dual chains
                    SAMP(posA, a0);
                    SAMP(posB, a1);
                    posA += st2; posB += st2;
                }
                if (n & 1) SAMP(posA, a0);
                acc[k] += a0 + a1;
            }
        }
    }

#pragma unroll
    for (int k = 0; k < 4; ++k) {               // wave-coalesced 256B segments
        const int a = (g << 3) | (k << 1) | sub;
        ws2[((((q2 << 2) + b) << 9) | a) * 256 + w] = acc[k];
    }
}

__global__ __launch_bounds__(256) void reduce_k(const float* __restrict__ ws2,
                                                float* __restrict__ out) {
    __shared__ float s[32][33];
    const int bx = blockIdx.x;                  // 512 = b(4) x at(16) x wt(8)
    const int wt = bx & 7, at = (bx >> 3) & 15, b = bx >> 7;
    const int a0 = at << 5, w0 = wt << 5;
    const int wl = threadIdx.x & 31, r8 = threadIdx.x >> 5;
#pragma unroll
    for (int p = 0; p < 4; ++p) {
        int ar = r8 + (p << 3);
        int a  = a0 + ar;
        float acc = 0.f;
#pragma unroll
        for (int qq = 0; qq < 8; ++qq)
            acc += ws2[(((((qq << 2) + b) << 9) | a) << 8) | (w0 + wl)];
        s[ar][wl] = acc;                        // s[a_local][w_local]
    }
    __syncthreads();
#pragma unroll
    for (int p = 0; p < 4; ++p) {
        int wr = r8 + (p << 3);
        out[(b << 17) | ((w0 + wr) << 9) | (a0 + wl)] = s[wl][wr];  // coalesced in a
    }
}

extern "C" void kernel_launch(void* const* d_in, const int* in_sizes, int n_in,
                              void* d_out, int out_size, void* d_ws, size_t ws_size,
                              hipStream_t stream) {
    const float* img = (const float*)d_in[0];
    float* out = (float*)d_out;
    float* ws2 = (float*)d_ws;                  // 16.8 MB: [q2][b][a][w]
    radon_k <<<dim3(2048), dim3(512), 0, stream>>>(img, ws2);
    reduce_k<<<dim3(512),  dim3(256), 0, stream>>>(ws2, out);
}

// Round 8
// 169.523 us; speedup vs baseline: 1.3424x; 1.3424x over previous
//
#include <hip/hip_runtime.h>

// Radon transform, MI355X. B=4, IMG=256, NA=512.
// R8 = proven pieces only. Quad layout (1 ds_read_b64/sample) + 16-row slabs
// (39 KB -> 4 blocks/CU, 32 waves) + transpose_k restored so col-mode staging
// is coalesced (R7's direct strided staging stalled whole blocks at barriers)
// + 3 accumulator chains (24 outstanding b64/SIMD covers LDS latency).
// Blocks do 2 sequential 16-row slabs (1 restage) so ws partials stay 16.8 MB.

typedef _Float16 f16;
typedef _Float16 f16x2 __attribute__((ext_vector_type(2)));
typedef _Float16 f16x4 __attribute__((ext_vector_type(4)));
typedef __fp16   h16x2 __attribute__((ext_vector_type(2)));
typedef float    f32x2 __attribute__((ext_vector_type(2)));

#define CST   19                 // quad col stride in 8B words
#define NQR   18                 // quad rows per slab (Ri in [0,17])
#define NC    257                // pair-columns X = 0..256
#define LDSQ  (NC * CST)         // 4883 8B words = 39,064 B -> 4 blocks/CU

// one bilinear sample: quad (X,Ri) = {P[r][X-1],P[r][X],P[r+1][X-1],P[r+1][X]},
// r = rbase+Ri. ONE ds_read_b64; packed f16 vertical lerp; fdot2 epilogue.
// med3 clamps: pc<0 / pc>257-eps and pr<0 (q=0) / pr>18-eps (q=15) all resolve
// to zero-weight or zero-tap reads (audited R5/R7).
#define SAMP(POS, ACC) do {                                       \
    float pc_ = __builtin_amdgcn_fmed3f((POS).x, 0.0f, 256.999f); \
    float pr_ = __builtin_amdgcn_fmed3f((POS).y, 0.0f, 17.999f);  \
    int   Xi_ = (int)pc_;                                         \
    int   Ri_ = (int)pr_;                                         \
    float wc_ = __builtin_amdgcn_fractf(pc_);                     \
    float wr_ = __builtin_amdgcn_fractf(pr_);                     \
    f16x4 qd_ = lds4[Xi_ * CST + Ri_];                            \
    f16x2 lo_ = __builtin_shufflevector(qd_, qd_, 0, 1);          \
    f16x2 hi_ = __builtin_shufflevector(qd_, qd_, 2, 3);          \
    f16x2 wv_ = __builtin_bit_cast(f16x2, __builtin_amdgcn_cvt_pkrtz(wr_, wr_)); \
    f16x2 t_  = lo_ + wv_ * (hi_ - lo_);                          \
    h16x2 wp_ = __builtin_amdgcn_cvt_pkrtz(1.0f - wc_, wc_);      \
    (ACC) = __builtin_amdgcn_fdot2(__builtin_bit_cast(h16x2, t_), wp_, (ACC), false); \
} while (0)

__global__ __launch_bounds__(256) void transpose_k(const float* __restrict__ img,
                                                   float* __restrict__ imT) {
    __shared__ float tl[32][33];
    const int bx = blockIdx.x;                    // 256 = b(4) x ty(8) x tx(8)
    const int x0 = (bx & 7) << 5, y0 = ((bx >> 3) & 7) << 5, b = bx >> 6;
    const int lane = threadIdx.x & 31, rw = threadIdx.x >> 5;
    const float* ib = img + (b << 16);
    float*       tb = imT + (b << 16);
#pragma unroll
    for (int p = 0; p < 4; ++p) {
        int row = rw + (p << 3);
        tl[row][lane] = ib[((y0 + row) << 8) + x0 + lane];
    }
    __syncthreads();
#pragma unroll
    for (int p = 0; p < 4; ++p) {
        int row = rw + (p << 3);
        tb[((x0 + row) << 8) + y0 + lane] = tl[lane][row];
    }
}

__global__ __launch_bounds__(512, 8) void radon_k(const float* __restrict__ img,
                                                  const float* __restrict__ imT,
                                                  float* __restrict__ ws2) {
    __shared__ f16x4 lds4[LDSQ];
    const int tid = threadIdx.x;
    const int bx  = blockIdx.x;                 // 2048 = b(4) x g(64) x q2(8)
    const int q2 = bx & 7, g = (bx >> 3) & 63, b = bx >> 9;
    const bool colC = (g >= 16) && (g < 48);    // a in [128,384): column slabs
    const float* src = (colC ? imT : img) + (b << 16);

    const int   w   = tid & 255, sub = tid >> 8;  // angle uniform per wave
    const float xw  = (float)w - 127.5f;

    float acc[4] = {0.f, 0.f, 0.f, 0.f};

    for (int s = 0; s < 2; ++s) {
        const int q = (q2 << 1) | s;            // slab 0..15
        const int rbase = (q << 4) - 1;         // 19 staged rows: rbase..rbase+18
        if (s) __syncthreads();                 // drain slab-0 compute

        // ---- stage: u -> (rr, X), X fastest -> coalesced for both modes
        // (col-mode reads the transposed copy)
        for (int u = tid; u < NC * NQR; u += 512) {
            int rr = u / NC;                    // 0..17
            int X  = u - rr * NC;               // 0..256
            int r0 = rbase + rr;                // quad rows r0, r0+1
            float a0 = 0.f, b0 = 0.f, a1 = 0.f, b1 = 0.f;
            const float* rp = src + (r0 << 8);
            const bool c0 = X > 0, c1 = X < 256;
            if ((unsigned)r0 < 256u) {
                if (c0) a0 = rp[X - 1];
                if (c1) b0 = rp[X];
            }
            if ((unsigned)(r0 + 1) < 256u) {
                if (c0) a1 = rp[256 + X - 1];
                if (c1) b1 = rp[256 + X];
            }
            f16x4 w4; w4.x = (f16)a0; w4.y = (f16)b0; w4.z = (f16)a1; w4.w = (f16)b1;
            lds4[X * CST + rr] = w4;
        }
        __syncthreads();

        // band [B0,B1) on the slab axis
        const float B0 = (q == 0)  ? -1.0f  : (float)(q << 4);
        const float B1 = (q == 15) ? 256.0f : (float)((q << 4) + 16);

#pragma unroll
        for (int k = 0; k < 4; ++k) {
            const int a = (g << 3) | (k << 1) | sub;
            const float th  = (float)a * 6.1359231515425649e-3f;   // a*pi/512
            const float sth = __sinf(th), cth = __cosf(th);        // block-consistent
            const float Ax = fmaf(cth, xw, fmaf(sth, -127.5f, 127.5f));
            const float Ay = fmaf(-sth, xw, fmaf(cth, -127.5f, 127.5f));
            float cs, As, rs, Ar;                // col coord / slab coord roles
            if (colC) { cs = cth; As = Ay; rs = sth; Ar = Ax; }
            else      { cs = sth; As = Ax; rs = cth; Ar = Ay; }

            // slab ownership: r(h)=Ar+h*rs in [B0,B1); |rs|>=0.707; exact
            // ceil/floor partition (adjacent q share identical boundary floats)
            const float invr = 1.0f / rs;
            const float tA = (B0 - Ar) * invr, tB = (B1 - Ar) * invr;
            int h0, h1;
            if (rs > 0.f) { h0 = (int)ceilf(tA);      h1 = (int)ceilf(tB) - 1; }
            else          { h0 = (int)floorf(tB) + 1; h1 = (int)floorf(tA);   }

            // col validity v(h)=As+h*cs in (-1,256); cs signed, may be ~0
            if (cs != 0.f) {
                const float invc = 1.0f / cs;
                float ta = (-1.0f - As) * invc, tb = (256.0f - As) * invc;
                ta = fmaxf(fminf(ta, 400.f), -400.f);
                tb = fmaxf(fminf(tb, 400.f), -400.f);
                if (cs > 0.f) { h0 = max(h0, (int)ceilf(ta));      h1 = min(h1, (int)ceilf(tb) - 1); }
                else          { h0 = max(h0, (int)floorf(tb) + 1); h1 = min(h1, (int)floorf(ta));   }
            } else if (As <= -1.f || As >= 256.f) {
                h1 = h0 - 1;
            }
            h0 = max(h0, 0); h1 = min(h1, 255);

            if (h0 <= h1) {
                const float h0f = (float)h0;
                f32x2 pos0, st;
                pos0.x = fmaf(h0f, cs, As + 1.0f);           // col coord + 1
                pos0.y = fmaf(h0f, rs, Ar - (float)rbase);   // slab-local row
                st.x = cs; st.y = rs;
                f32x2 pA = pos0, pB = pos0 + st, pC = pB + st;
                const f32x2 st3 = st + st + st;
                float a0 = 0.f, a1 = 0.f, a2 = 0.f;
                const int n = h1 - h0 + 1;                   // <= 24
                int i = 0;
                for (; i + 3 <= n; i += 3) {                 // triple chains
                    SAMP(pA, a0);
                    SAMP(pB, a1);
                    SAMP(pC, a2);
                    pA += st3; pB += st3; pC += st3;
                }
                if (i + 1 <= n) SAMP(pA, a0);
                if (i + 2 <= n) SAMP(pB, a1);
                acc[k] += a0 + a1 + a2;
            }
        }
    }

#pragma unroll
    for (int k = 0; k < 4; ++k) {               // wave-coalesced 256B segments
        const int a = (g << 3) | (k << 1) | sub;
        ws2[((((q2 << 2) + b) << 9) | a) * 256 + w] = acc[k];
    }
}

__global__ __launch_bounds__(256) void reduce_k(const float* __restrict__ ws2,
                                                float* __restrict__ out) {
    __shared__ float s[32][33];
    const int bx = blockIdx.x;                  // 512 = b(4) x at(16) x wt(8)
    const int wt = bx & 7, at = (bx >> 3) & 15, b = bx >> 7;
    const int a0 = at << 5, w0 = wt << 5;
    const int wl = threadIdx.x & 31, r8 = threadIdx.x >> 5;
#pragma unroll
    for (int p = 0; p < 4; ++p) {
        int ar = r8 + (p << 3);
        int a  = a0 + ar;
        float acc = 0.f;
#pragma unroll
        for (int qq = 0; qq < 8; ++qq)
            acc += ws2[(((((qq << 2) + b) << 9) | a) << 8) | (w0 + wl)];
        s[ar][wl] = acc;                        // s[a_local][w_local]
    }
    __syncthreads();
#pragma unroll
    for (int p = 0; p < 4; ++p) {
        int wr = r8 + (p << 3);
        out[(b << 17) | ((w0 + wr) << 9) | (a0 + wl)] = s[wl][wr];  // coalesced in a
    }
}

extern "C" void kernel_launch(void* const* d_in, const int* in_sizes, int n_in,
                              void* d_out, int out_size, void* d_ws, size_t ws_size,
                              hipStream_t stream) {
    const float* img = (const float*)d_in[0];
    float* out = (float*)d_out;
    float* imT = (float*)d_ws;                  // 1 MB transposed copy
    float* ws2 = (float*)d_ws + (1 << 18);      // 16.8 MB: [q2][b][a][w]
    transpose_k<<<dim3(256),  dim3(256), 0, stream>>>(img, imT);
    radon_k   <<<dim3(2048), dim3(512), 0, stream>>>(img, imT, ws2);
    reduce_k  <<<dim3(512),  dim3(256), 0, stream>>>(ws2, out);
}